// Round 4
// baseline (259.889 us; speedup 1.0000x reference)
//
#include <hip/hip_runtime.h>

#define KTOP 64
#define GX   32
#define NCELL (GX*GX)
#define CSF  3.2f
#define X0F  -51.2f

// Anti-contraction barrier: force f32 rounding points to match the reference.
#define BAR(x) asm volatile("" : "+v"(x))

// -------- binning helpers (f64, conservative margins) --------
__device__ inline void g_reach_cells(float s0, float s1, float s2,
                                     float m0, float m1,
                                     int& cx0, int& cx1, int& cy0, int& cy1,
                                     double& mux, double& muy, double& reach2)
{
    const double ss0 = (double)s0 * (double)s0 + 1e-8;
    const double ss1 = (double)s1 * (double)s1 + 1e-8;
    const double ss2 = (double)s2 * (double)s2 + 1e-8;
    double smax = ss0 > ss1 ? ss0 : ss1; smax = smax > ss2 ? smax : ss2;
    const double sum = ss0 + ss1 + ss2;
    reach2 = 9.0 * smax * sum * 1.0005 + 1e-4;   // covers all f32 rounding of d2/r2
    const double reach = sqrt(reach2);
    mux = (double)m0; muy = (double)m1;
    cx0 = (int)floor((mux - reach - (double)X0F) / (double)CSF);
    cx1 = (int)floor((mux + reach - (double)X0F) / (double)CSF);
    cy0 = (int)floor((muy - reach - (double)X0F) / (double)CSF);
    cy1 = (int)floor((muy + reach - (double)X0F) / (double)CSF);
    cx0 = cx0 < 0 ? 0 : cx0;  cy0 = cy0 < 0 ? 0 : cy0;
    cx1 = cx1 > GX-1 ? GX-1 : cx1;  cy1 = cy1 > GX-1 ? GX-1 : cy1;
}

__device__ inline bool cell_hits(int cx, int cy, double mux, double muy, double reach2)
{
    const double lx = (double)X0F + (double)cx * (double)CSF - 1e-4;
    const double hx = lx + (double)CSF + 2e-4;
    const double ly = (double)X0F + (double)cy * (double)CSF - 1e-4;
    const double hy = ly + (double)CSF + 2e-4;
    double dx = 0.0, dy = 0.0;
    if (mux < lx) dx = lx - mux; else if (mux > hx) dx = mux - hx;
    if (muy < ly) dy = ly - muy; else if (muy > hy) dy = muy - hy;
    return dx*dx + dy*dy <= reach2;
}

// -------- kernel 1: zero the cell counts --------
__global__ __launch_bounds__(1024)
void k_zero(int* __restrict__ counts)
{
    counts[threadIdx.x] = 0;
}

// -------- kernel 2: per-gaussian params (bit-exact) + cell counts --------
__global__ __launch_bounds__(256)
void k_params_count(const float* __restrict__ mu,
                    const float* __restrict__ scale,
                    float* __restrict__ params,
                    int* __restrict__ counts, int N)
{
    const int g = blockIdx.x * 256 + threadIdx.x;
    if (g >= N) return;
    const float s0 = scale[3*g+0], s1 = scale[3*g+1], s2 = scale[3*g+2];
    const float m0 = mu[3*g+0],    m1 = mu[3*g+1],    m2 = mu[3*g+2];

    // ---- proven bit-exact f32 param derivation (rounds 2/3) ----
    float s0s = s0 * s0; BAR(s0s);
    float s1s = s1 * s1; BAR(s1s);
    float s2s = s2 * s2; BAR(s2s);
    float d0 = s0s + 1e-8f;
    float d1 = s1s + 1e-8f;
    float dd2 = s2s + 1e-8f;
    float i0 = 1.0f / d0;
    float i1 = 1.0f / d1;
    float i2 = 1.0f / dd2;
    float mi0 = m0 * i0; BAR(mi0);
    float mi1 = m1 * i1; BAR(mi1);
    float mi2 = m2 * i2; BAR(mi2);
    float p0 = m0 * mi0; BAR(p0);
    float p1 = m1 * mi1; BAR(p1);
    float p2 = m2 * mi2; BAR(p2);
    float mt = (p0 + p1) + p2;
    float rs = (s0s + s1s) + s2s;
    float r2 = 9.0f * rs;
    *(float4*)&params[(size_t)g*8]     = make_float4(i0, i1, i2, mi0);
    *(float4*)&params[(size_t)g*8 + 4] = make_float4(mi1, mi2, mt, r2);

    int cx0, cx1, cy0, cy1; double mux, muy, reach2;
    g_reach_cells(s0, s1, s2, m0, m1, cx0, cx1, cy0, cy1, mux, muy, reach2);
    for (int cy = cy0; cy <= cy1; ++cy)
        for (int cx = cx0; cx <= cx1; ++cx)
            if (cell_hits(cx, cy, mux, muy, reach2))
                atomicAdd(&counts[cy*GX + cx], 1);
}

// -------- kernel 3: prefix sum over 1024 cells --------
__global__ __launch_bounds__(1024)
void k_prefix(const int* __restrict__ counts,
              int* __restrict__ offsets,
              int* __restrict__ cursors)
{
    __shared__ int sm[NCELL];
    const int t = threadIdx.x;
    const int v = counts[t];
    sm[t] = v;
    __syncthreads();
    for (int d = 1; d < NCELL; d <<= 1) {
        int a = (t >= d) ? sm[t - d] : 0;
        __syncthreads();
        sm[t] += a;
        __syncthreads();
    }
    offsets[t + 1] = sm[t];
    if (t == 0) offsets[0] = 0;
    cursors[t] = sm[t] - v;   // exclusive prefix
}

// -------- kernel 4: scatter gaussian ids into cell lists --------
__global__ __launch_bounds__(256)
void k_scatter(const float* __restrict__ mu,
               const float* __restrict__ scale,
               int* __restrict__ cursors,
               unsigned short* __restrict__ entries, int N)
{
    const int g = blockIdx.x * 256 + threadIdx.x;
    if (g >= N) return;
    const float s0 = scale[3*g+0], s1 = scale[3*g+1], s2 = scale[3*g+2];
    const float m0 = mu[3*g+0],    m1 = mu[3*g+1];
    int cx0, cx1, cy0, cy1; double mux, muy, reach2;
    g_reach_cells(s0, s1, s2, m0, m1, cx0, cx1, cy0, cy1, mux, muy, reach2);
    for (int cy = cy0; cy <= cy1; ++cy)
        for (int cx = cx0; cx <= cx1; ++cx)
            if (cell_hits(cx, cy, mux, muy, reach2)) {
                int pos = atomicAdd(&cursors[cy*GX + cx], 1);
                entries[pos] = (unsigned short)g;
            }
}

// -------- kernel 5: per-query scan of its cell list --------
__global__ __launch_bounds__(128)
void k_scan(const int* __restrict__ vox,
            const float* __restrict__ pcr,
            const float* __restrict__ params,
            const unsigned short* __restrict__ entries,
            const int* __restrict__ offsets,
            float* __restrict__ out, int M)
{
    const int q = blockIdx.x * 128 + threadIdx.x;
    if (q >= M) return;

    const float pc0 = pcr[0], pc1 = pcr[1], pc2 = pcr[2];
    int4 c = ((const int4*)vox)[q];   // (b, z, y, x)
    const int iz = c.y, iy = c.z, ix = c.w;

    // centers: bit-exact f32 (proven)
    float tx = ((float)ix + 0.5f) * 0.2f; BAR(tx);
    float ty = ((float)iy + 0.5f) * 0.2f; BAR(ty);
    float tz = ((float)iz + 0.5f) * 0.2f; BAR(tz);
    const float qx = pc0 + tx;
    const float qy = pc1 + ty;
    const float qz = pc2 + tz;
    float qx2 = qx * qx; BAR(qx2);
    float qy2 = qy * qy; BAR(qy2);
    float qz2 = qz * qz; BAR(qz2);

    out[3 * (size_t)q + 0] = qx;
    out[3 * (size_t)q + 1] = qy;
    out[3 * (size_t)q + 2] = qz;

    int cx = (int)floorf((qx - X0F) * (1.0f / CSF));
    int cy = (int)floorf((qy - X0F) * (1.0f / CSF));
    cx = cx < 0 ? 0 : (cx > GX-1 ? GX-1 : cx);
    cy = cy < 0 ? 0 : (cy > GX-1 ? GX-1 : cy);
    const int cell = cy * GX + cx;
    const int beg = offsets[cell];
    const int end = offsets[cell + 1];

    float key[KTOP];
    int   gi[KTOP];
    int   cnt = 0;

    #pragma unroll 2
    for (int i = beg; i < end; ++i) {
        const int g = entries[i];
        const float4 pa = *(const float4*)&params[(size_t)g*8];
        const float4 pb = *(const float4*)&params[(size_t)g*8 + 4];
        // proven bit-exact d2: BLAS fma-chain dots, fma(-2,t2,t1)+mt
        float t1 = __builtin_fmaf(qz2, pa.z, __builtin_fmaf(qy2, pa.y, qx2 * pa.x));
        float t2 = __builtin_fmaf(qz,  pb.y, __builtin_fmaf(qy,  pb.x, qx  * pa.w));
        const float d2v = (t1 - 2.0f * t2) + pb.z;
        if (d2v <= pb.w) {
            int j;
            if (cnt < KTOP) {
                j = cnt++;
            } else {
                const float lk = key[KTOP-1]; const int lg = gi[KTOP-1];
                if (d2v < lk || (d2v == lk && g < lg)) j = KTOP - 1;
                else continue;
            }
            while (j > 0 && (key[j-1] > d2v || (key[j-1] == d2v && gi[j-1] > g))) {
                key[j] = key[j-1]; gi[j] = gi[j-1]; --j;
            }
            key[j] = d2v; gi[j] = g;
        }
    }

    float* idxb = out + 3 * (size_t)M;
    float* wb   = idxb + (size_t)M * KTOP;
    float* mb   = wb   + (size_t)M * KTOP;
    const size_t base = (size_t)q * KTOP;
    for (int k = 0; k < KTOP; ++k) {
        const bool v = (k < cnt);
        idxb[base + k] = v ? (float)gi[k] : -1.0f;
        wb[base + k]   = v ? key[k] : 0.0f;
        mb[base + k]   = v ? 1.0f : 0.0f;
    }
}

extern "C" void kernel_launch(void* const* d_in, const int* in_sizes, int n_in,
                              void* d_out, int out_size, void* d_ws, size_t ws_size,
                              hipStream_t stream)
{
    const int*   vox   = (const int*)d_in[0];
    const float* mu    = (const float*)d_in[1];
    const float* scale = (const float*)d_in[2];
    const float* pcr   = (const float*)d_in[3];
    float* out = (float*)d_out;

    const int M = in_sizes[0] / 4;
    const int N = in_sizes[1] / 3;

    // ws layout (256-aligned chunks)
    char* ws = (char*)d_ws;
    const size_t entries_cap = (size_t)N * 25 + 64;
    size_t o = 0;
    float* params = (float*)(ws + o);              o += ((size_t)N * 32 + 255) & ~(size_t)255;
    unsigned short* entries = (unsigned short*)(ws + o); o += (entries_cap * 2 + 255) & ~(size_t)255;
    int* counts  = (int*)(ws + o);                 o += (NCELL * 4 + 255) & ~(size_t)255;
    int* offsets = (int*)(ws + o);                 o += ((NCELL + 1) * 4 + 255) & ~(size_t)255;
    int* cursors = (int*)(ws + o);                 o += (NCELL * 4 + 255) & ~(size_t)255;

    hipLaunchKernelGGL(k_zero, dim3(1), dim3(NCELL), 0, stream, counts);
    hipLaunchKernelGGL(k_params_count, dim3((N + 255) / 256), dim3(256), 0, stream,
                       mu, scale, params, counts, N);
    hipLaunchKernelGGL(k_prefix, dim3(1), dim3(NCELL), 0, stream,
                       counts, offsets, cursors);
    hipLaunchKernelGGL(k_scatter, dim3((N + 255) / 256), dim3(256), 0, stream,
                       mu, scale, cursors, entries, N);
    hipLaunchKernelGGL(k_scan, dim3((M + 127) / 128), dim3(128), 0, stream,
                       vox, pcr, params, entries, offsets, out, M);
}

// Round 5
// 202.282 us; speedup vs baseline: 1.2848x; 1.2848x over previous
//
#include <hip/hip_runtime.h>

#define KTOP 64
#define GX   32
#define NCELL (GX*GX)
#define CSF  3.2f
#define X0F  -51.2f
#define SPL  8
#define TPB2 512
#define TROWS 768

// Anti-contraction barrier: force f32 rounding points to match the reference.
#define BAR(x) asm volatile("" : "+v"(x))

// -------- binning helpers (f64, conservative margins) --------
__device__ inline void g_reach_cells(float s0, float s1, float s2,
                                     float m0, float m1,
                                     int& cx0, int& cx1, int& cy0, int& cy1,
                                     double& mux, double& muy, double& reach2)
{
    const double ss0 = (double)s0 * (double)s0 + 1e-8;
    const double ss1 = (double)s1 * (double)s1 + 1e-8;
    const double ss2 = (double)s2 * (double)s2 + 1e-8;
    double smax = ss0 > ss1 ? ss0 : ss1; smax = smax > ss2 ? smax : ss2;
    const double sum = ss0 + ss1 + ss2;
    // Euclid^2 bound: |q-mu|^2 <= smax * d2 <= smax * 9*sum.
    // +0.5 absolute slack covers f32 d2 rounding (~0.25) * smax (~1.2) + grid-map noise.
    reach2 = 9.0 * smax * sum * 1.0005 + 0.5;
    const double reach = sqrt(reach2);
    mux = (double)m0; muy = (double)m1;
    cx0 = (int)floor((mux - reach - (double)X0F) / (double)CSF);
    cx1 = (int)floor((mux + reach - (double)X0F) / (double)CSF);
    cy0 = (int)floor((muy - reach - (double)X0F) / (double)CSF);
    cy1 = (int)floor((muy + reach - (double)X0F) / (double)CSF);
    cx0 = cx0 < 0 ? 0 : cx0;  cy0 = cy0 < 0 ? 0 : cy0;
    cx1 = cx1 > GX-1 ? GX-1 : cx1;  cy1 = cy1 > GX-1 ? GX-1 : cy1;
}

__device__ inline bool cell_hits(int cx, int cy, double mux, double muy, double reach2)
{
    const double lx = (double)X0F + (double)cx * (double)CSF - 1e-3;
    const double hx = lx + (double)CSF + 2e-3;
    const double ly = (double)X0F + (double)cy * (double)CSF - 1e-3;
    const double hy = ly + (double)CSF + 2e-3;
    double dx = 0.0, dy = 0.0;
    if (mux < lx) dx = lx - mux; else if (mux > hx) dx = mux - hx;
    if (muy < ly) dy = ly - muy; else if (muy > hy) dy = muy - hy;
    return dx*dx + dy*dy <= reach2;
}

// query center (bit-exact f32, proven) + its cell
__device__ inline void q_center(int ix, int iy, int iz, float pc0, float pc1, float pc2,
                                float& qx, float& qy, float& qz)
{
    float tx = ((float)ix + 0.5f) * 0.2f; BAR(tx);
    float ty = ((float)iy + 0.5f) * 0.2f; BAR(ty);
    float tz = ((float)iz + 0.5f) * 0.2f; BAR(tz);
    qx = pc0 + tx;  qy = pc1 + ty;  qz = pc2 + tz;
}

__device__ inline int q_cell(float qx, float qy)
{
    int cx = (int)floorf((qx - X0F) * (1.0f / CSF));
    int cy = (int)floorf((qy - X0F) * (1.0f / CSF));
    cx = cx < 0 ? 0 : (cx > GX-1 ? GX-1 : cx);
    cy = cy < 0 ? 0 : (cy > GX-1 ? GX-1 : cy);
    return cy * GX + cx;
}

// -------- kernel 1: zero both counter arrays (2*NCELL ints) --------
__global__ __launch_bounds__(1024)
void k_zero(int* __restrict__ cnts)
{
    cnts[blockIdx.x * 1024 + threadIdx.x] = 0;
}

// -------- kernel 2: gaussian params+counts AND query centers+counts --------
__global__ __launch_bounds__(256)
void k_count(const float* __restrict__ mu, const float* __restrict__ scale,
             const int* __restrict__ vox, const float* __restrict__ pcr,
             float* __restrict__ params, int* __restrict__ gcnt, int* __restrict__ qcnt,
             float* __restrict__ out, int N, int M, int GB)
{
    const int b = blockIdx.x;
    if (b < GB) {
        const int g = b * 256 + threadIdx.x;
        if (g >= N) return;
        const float s0 = scale[3*g+0], s1 = scale[3*g+1], s2 = scale[3*g+2];
        const float m0 = mu[3*g+0],    m1 = mu[3*g+1],    m2 = mu[3*g+2];
        // proven bit-exact f32 param derivation
        float s0s = s0 * s0; BAR(s0s);
        float s1s = s1 * s1; BAR(s1s);
        float s2s = s2 * s2; BAR(s2s);
        float d0 = s0s + 1e-8f;
        float d1 = s1s + 1e-8f;
        float dd2 = s2s + 1e-8f;
        float i0 = 1.0f / d0;
        float i1 = 1.0f / d1;
        float i2 = 1.0f / dd2;
        float mi0 = m0 * i0; BAR(mi0);
        float mi1 = m1 * i1; BAR(mi1);
        float mi2 = m2 * i2; BAR(mi2);
        float p0 = m0 * mi0; BAR(p0);
        float p1 = m1 * mi1; BAR(p1);
        float p2 = m2 * mi2; BAR(p2);
        float mt = (p0 + p1) + p2;
        float rs = (s0s + s1s) + s2s;
        float r2 = 9.0f * rs;
        *(float4*)&params[(size_t)g*8]     = make_float4(i0, i1, i2, mi0);
        *(float4*)&params[(size_t)g*8 + 4] = make_float4(mi1, mi2, mt, r2);

        int cx0, cx1, cy0, cy1; double mux, muy, reach2;
        g_reach_cells(s0, s1, s2, m0, m1, cx0, cx1, cy0, cy1, mux, muy, reach2);
        for (int cy = cy0; cy <= cy1; ++cy)
            for (int cx = cx0; cx <= cx1; ++cx)
                if (cell_hits(cx, cy, mux, muy, reach2))
                    atomicAdd(&gcnt[cy*GX + cx], 1);
    } else {
        const int q = (b - GB) * 256 + threadIdx.x;
        if (q >= M) return;
        int4 c = ((const int4*)vox)[q];   // (b, z, y, x)
        float qx, qy, qz;
        q_center(c.w, c.z, c.y, pcr[0], pcr[1], pcr[2], qx, qy, qz);
        out[3*(size_t)q + 0] = qx;
        out[3*(size_t)q + 1] = qy;
        out[3*(size_t)q + 2] = qz;
        atomicAdd(&qcnt[q_cell(qx, qy)], 1);
    }
}

// -------- kernel 3: prefix sums for both counter arrays --------
__global__ __launch_bounds__(1024)
void k_prefix2(const int* __restrict__ gcnt, const int* __restrict__ qcnt,
               int* __restrict__ goff, int* __restrict__ qoff,
               int* __restrict__ gcur, int* __restrict__ qcur)
{
    __shared__ int sm[NCELL];
    const int t = threadIdx.x;
    {
        const int v = gcnt[t];
        sm[t] = v; __syncthreads();
        for (int d = 1; d < NCELL; d <<= 1) {
            int a = (t >= d) ? sm[t - d] : 0;
            __syncthreads(); sm[t] += a; __syncthreads();
        }
        goff[t + 1] = sm[t]; if (t == 0) goff[0] = 0;
        gcur[t] = sm[t] - v;
        __syncthreads();
    }
    {
        const int v = qcnt[t];
        sm[t] = v; __syncthreads();
        for (int d = 1; d < NCELL; d <<= 1) {
            int a = (t >= d) ? sm[t - d] : 0;
            __syncthreads(); sm[t] += a; __syncthreads();
        }
        qoff[t + 1] = sm[t]; if (t == 0) qoff[0] = 0;
        qcur[t] = sm[t] - v;
    }
}

// -------- kernel 4: scatter gaussians AND queries into cell lists --------
__global__ __launch_bounds__(256)
void k_scatter(const float* __restrict__ mu, const float* __restrict__ scale,
               const int* __restrict__ vox, const float* __restrict__ pcr,
               int* __restrict__ gcur, int* __restrict__ qcur,
               unsigned short* __restrict__ entries, int* __restrict__ qids,
               int N, int M, int GB)
{
    const int b = blockIdx.x;
    if (b < GB) {
        const int g = b * 256 + threadIdx.x;
        if (g >= N) return;
        const float s0 = scale[3*g+0], s1 = scale[3*g+1], s2 = scale[3*g+2];
        const float m0 = mu[3*g+0],    m1 = mu[3*g+1];
        int cx0, cx1, cy0, cy1; double mux, muy, reach2;
        g_reach_cells(s0, s1, s2, m0, m1, cx0, cx1, cy0, cy1, mux, muy, reach2);
        for (int cy = cy0; cy <= cy1; ++cy)
            for (int cx = cx0; cx <= cx1; ++cx)
                if (cell_hits(cx, cy, mux, muy, reach2)) {
                    int pos = atomicAdd(&gcur[cy*GX + cx], 1);
                    entries[pos] = (unsigned short)g;
                }
    } else {
        const int q = (b - GB) * 256 + threadIdx.x;
        if (q >= M) return;
        int4 c = ((const int4*)vox)[q];
        float qx, qy, qz;
        q_center(c.w, c.z, c.y, pcr[0], pcr[1], pcr[2], qx, qy, qz);
        int pos = atomicAdd(&qcur[q_cell(qx, qy)], 1);
        qids[pos] = q;
    }
}

// -------- kernel 5: per-cell scan, 8-way split + lex extract-min merge --------
__global__ __launch_bounds__(TPB2)
void k_scan(const int* __restrict__ vox, const float* __restrict__ pcr,
            const float* __restrict__ params,
            const unsigned short* __restrict__ entries, const int* __restrict__ goff,
            const int* __restrict__ qids, const int* __restrict__ qoff,
            float* __restrict__ out, int M)
{
    __shared__ float Pa[TROWS][8];     // staged param rows (24 KB)
    __shared__ int   Pg[TROWS];        // gaussian id per row (3 KB)
    __shared__ float headk[SPL][64];
    __shared__ int   headi[SPL][64];
    __shared__ int   cnt_l[SPL][64];
    __shared__ int   win[64];
    __shared__ int   Rsh;

    const int cell = blockIdx.x;
    const int tid = threadIdx.x;
    const int s = tid >> 6;            // split id (wave)
    const int l = tid & 63;            // lane = local query
    const int qb = qoff[cell], qe = qoff[cell + 1];
    const int gb = goff[cell], ge = goff[cell + 1];
    const int L = ge - gb;
    const float INF = __builtin_inff();

    const float pc0 = pcr[0], pc1 = pcr[1], pc2 = pcr[2];

    float* idxb = out + 3 * (size_t)M;
    float* wb   = idxb + (size_t)M * KTOP;
    float* mb   = wb   + (size_t)M * KTOP;

    for (int q0 = qb; q0 < qe; q0 += 64) {
        const int nq = (qe - q0 < 64) ? (qe - q0) : 64;
        const bool act = (l < nq);
        const int q = act ? qids[q0 + l] : 0;

        float qx = 0.f, qy = 0.f, qz = 0.f;
        if (act) {
            int4 c = ((const int4*)vox)[q];
            q_center(c.w, c.z, c.y, pc0, pc1, pc2, qx, qy, qz);
        }
        float qx2 = qx * qx; BAR(qx2);
        float qy2 = qy * qy; BAR(qy2);
        float qz2 = qz * qz; BAR(qz2);

        float key[KTOP];
        int   gi[KTOP];
        int   cnt = 0;

        for (int t0 = 0; t0 < L; t0 += TROWS) {
            const int rows = (L - t0 < TROWS) ? (L - t0) : TROWS;
            __syncthreads();   // previous LDS consumers done
            for (int r = tid; r < rows * 2; r += TPB2) {
                const int row = r >> 1, half = r & 1;
                const int g = entries[gb + t0 + row];
                float4 v = *(const float4*)&params[(size_t)g * 8 + half * 4];
                *(float4*)&Pa[row][half * 4] = v;
                if (half == 0) Pg[row] = g;
            }
            __syncthreads();

            if (act) {
                const int r0 = (s * rows) >> 3;
                const int r1 = ((s + 1) * rows) >> 3;
                for (int i = r0; i < r1; ++i) {
                    const float4 pa = *(const float4*)&Pa[i][0];
                    const float4 pb = *(const float4*)&Pa[i][4];
                    // proven bit-exact d2
                    float t1 = __builtin_fmaf(qz2, pa.z, __builtin_fmaf(qy2, pa.y, qx2 * pa.x));
                    float t2 = __builtin_fmaf(qz,  pb.y, __builtin_fmaf(qy,  pb.x, qx  * pa.w));
                    const float d2v = (t1 - 2.0f * t2) + pb.z;
                    if (d2v <= pb.w) {
                        const int g = Pg[i];
                        int j;
                        if (cnt < KTOP) {
                            j = cnt++;
                        } else {
                            const float lk = key[KTOP-1]; const int lg = gi[KTOP-1];
                            if (d2v < lk || (d2v == lk && g < lg)) j = KTOP - 1;
                            else continue;
                        }
                        while (j > 0 && (key[j-1] > d2v || (key[j-1] == d2v && gi[j-1] > g))) {
                            key[j] = key[j-1]; gi[j] = gi[j-1]; --j;
                        }
                        key[j] = d2v; gi[j] = g;
                    }
                }
            }
        }

        __syncthreads();
        cnt_l[s][l] = cnt;
        __syncthreads();

        if (s == 0) {
            int total = 0;
            #pragma unroll
            for (int s2 = 0; s2 < SPL; ++s2) total += cnt_l[s2][l];
            int myR = total < KTOP ? total : KTOP;
            for (int off = 32; off; off >>= 1) {
                int o = __shfl_xor(myR, off);
                myR = myR > o ? myR : o;
            }
            if (l == 0) Rsh = myR;
            win[l] = -1;
        }
        __syncthreads();
        const int R = Rsh;

        int p = 0;
        for (int r = 0; r < R; ++r) {
            headk[s][l] = (p < cnt) ? key[p] : INF;
            headi[s][l] = (p < cnt) ? gi[p]  : 0x7fffffff;
            __syncthreads();
            if (s == 0) {
                int wseg = -1, mg = 0x7fffffff;
                float m = INF;
                #pragma unroll
                for (int s2 = 0; s2 < SPL; ++s2) {   // lex (d2, g): global stable order
                    const float v = headk[s2][l];
                    const int   g2 = headi[s2][l];
                    if (v < m || (v == m && g2 < mg)) { m = v; mg = g2; wseg = s2; }
                }
                if (act) {
                    const size_t o = (size_t)q * KTOP + r;
                    if (wseg >= 0 && mg != 0x7fffffff) {
                        idxb[o] = (float)mg; wb[o] = m; mb[o] = 1.0f;
                    } else {
                        idxb[o] = -1.0f; wb[o] = 0.0f; mb[o] = 0.0f;
                    }
                }
                win[l] = wseg;
            }
            __syncthreads();
            if (win[l] == s) ++p;
        }

        if (act) {
            for (int k = R + s; k < KTOP; k += SPL) {
                const size_t o = (size_t)q * KTOP + k;
                idxb[o] = -1.0f; wb[o] = 0.0f; mb[o] = 0.0f;
            }
        }
        __syncthreads();   // win/heads reused next chunk
    }
}

extern "C" void kernel_launch(void* const* d_in, const int* in_sizes, int n_in,
                              void* d_out, int out_size, void* d_ws, size_t ws_size,
                              hipStream_t stream)
{
    const int*   vox   = (const int*)d_in[0];
    const float* mu    = (const float*)d_in[1];
    const float* scale = (const float*)d_in[2];
    const float* pcr   = (const float*)d_in[3];
    float* out = (float*)d_out;

    const int M = in_sizes[0] / 4;
    const int N = in_sizes[1] / 3;

    // ws layout (256-aligned)
    char* ws = (char*)d_ws;
    const size_t entries_cap = (size_t)N * 25 + 64;
    size_t o = 0;
    float* params = (float*)(ws + o);                    o += ((size_t)N * 32 + 255) & ~(size_t)255;
    unsigned short* entries = (unsigned short*)(ws + o); o += (entries_cap * 2 + 255) & ~(size_t)255;
    int* qids  = (int*)(ws + o);                         o += ((size_t)M * 4 + 255) & ~(size_t)255;
    int* cnts  = (int*)(ws + o);                         o += (2 * NCELL * 4 + 255) & ~(size_t)255;
    int* goff  = (int*)(ws + o);                         o += ((NCELL + 1) * 4 + 255) & ~(size_t)255;
    int* qoff  = (int*)(ws + o);                         o += ((NCELL + 1) * 4 + 255) & ~(size_t)255;
    int* gcur  = (int*)(ws + o);                         o += (NCELL * 4 + 255) & ~(size_t)255;
    int* qcur  = (int*)(ws + o);                         o += (NCELL * 4 + 255) & ~(size_t)255;
    int* gcnt = cnts;
    int* qcnt = cnts + NCELL;

    const int GB = (N + 255) / 256;
    const int QB = (M + 255) / 256;

    hipLaunchKernelGGL(k_zero, dim3(2), dim3(1024), 0, stream, cnts);
    hipLaunchKernelGGL(k_count, dim3(GB + QB), dim3(256), 0, stream,
                       mu, scale, vox, pcr, params, gcnt, qcnt, out, N, M, GB);
    hipLaunchKernelGGL(k_prefix2, dim3(1), dim3(1024), 0, stream,
                       gcnt, qcnt, goff, qoff, gcur, qcur);
    hipLaunchKernelGGL(k_scatter, dim3(GB + QB), dim3(256), 0, stream,
                       mu, scale, vox, pcr, gcur, qcur, entries, qids, N, M, GB);
    hipLaunchKernelGGL(k_scan, dim3(NCELL), dim3(TPB2), 0, stream,
                       vox, pcr, params, entries, goff, qids, qoff, out, M);
}